// Round 3
// baseline (218.753 us; speedup 1.0000x reference)
//
#include <hip/hip_runtime.h>
#include <hip/hip_bf16.h>

// Problem constants: b=4, n=8192, dim=256, heads=8, dhead=64, inner=512
#define SEQ    8192
#define NROWS  32768      // b*n
#define EPS    1e-5f

typedef __attribute__((ext_vector_type(4))) float f32x4;
typedef __attribute__((ext_vector_type(8))) short bf16x8;          // 8 bf16 (MFMA A/B frag)
typedef __attribute__((ext_vector_type(8))) unsigned short u16x8;  // 16B bf16 load/store

__device__ __forceinline__ unsigned short f2bu(float f) {
  __hip_bfloat16 h = __float2bfloat16(f);
  return __builtin_bit_cast(unsigned short, h);
}
__device__ __forceinline__ float b2f(unsigned short u) {
  return __bfloat162float(__builtin_bit_cast(__hip_bfloat16, u));
}

// ---------------------------------------------------------------- convert f32 -> bf16 (x4 vectorized)
__global__ __launch_bounds__(256) void convert_kernel(const float* __restrict__ in,
                                                      unsigned short* __restrict__ out, int n4) {
  int i = blockIdx.x * 256 + threadIdx.x;
  if (i >= n4) return;
  float4 v = reinterpret_cast<const float4*>(in)[i];
  ushort4 o;
  o.x = f2bu(v.x); o.y = f2bu(v.y); o.z = f2bu(v.z); o.w = f2bu(v.w);
  reinterpret_cast<ushort4*>(out)[i] = o;
}

// ---------------------------------------------------------------- weight prep: Wqkv f32 -> bf16 (all rows)
// plus transposed q-block: wqT[c, f] = Wqkv[f, c] for f<512 (for the W3 = M2 @ Wq fold)
__global__ __launch_bounds__(256) void wprep_kernel(const float* __restrict__ W,
                                                    unsigned short* __restrict__ wb,
                                                    unsigned short* __restrict__ wqT) {
  int i = blockIdx.x * 256 + threadIdx.x;     // 98304 float4 groups (1536*256/4)
  if (i >= 98304) return;
  float4 v = reinterpret_cast<const float4*>(W)[i];
  ushort4 o;
  o.x = f2bu(v.x); o.y = f2bu(v.y); o.z = f2bu(v.z); o.w = f2bu(v.w);
  reinterpret_cast<ushort4*>(wb)[i] = o;
  const int e = i * 4;
  const int f = e >> 8;                       // row in [0,1536)
  if (f < 512) {                              // q rows -> scatter transpose
    const int c = e & 255;
    wqT[(size_t)(c + 0) * 512 + f] = o.x;
    wqT[(size_t)(c + 1) * 512 + f] = o.y;
    wqT[(size_t)(c + 2) * 512 + f] = o.z;
    wqT[(size_t)(c + 3) * 512 + f] = o.w;
  }
}

// ---------------------------------------------------------------- bf16 MFMA GEMM: C[m,c] = sum_k A[m,k]*Bw[c,k]
// m97 structure: 128x128 tile, BK=64, 4 waves (2x2 of 64x64), global_load_lds width=16, 2-barrier loop.
// Grid: x = col blocks (fastest -> blocks sharing the A row-panel dispatch adjacently), y = row blocks.
// bf16 output path stages C in LDS and stores 16B-coalesced.
template<int K, int LDA, int LDC, bool PERB, bool BIAS, bool OUTF32>
__global__ __launch_bounds__(256) void gemm_kernel(const unsigned short* __restrict__ A,
                                                   const unsigned short* __restrict__ Bw,
                                                   const float* __restrict__ bias,
                                                   void* __restrict__ Cout) {
  __shared__ char smem[32768];
  unsigned short* As = (unsigned short*)smem;            // [128][64]
  unsigned short* Bs = (unsigned short*)(smem + 16384);  // [128][64]
  const int row0 = blockIdx.y * 128;
  const int col0 = blockIdx.x * 128;
  const unsigned short* Bp = Bw;
  if constexpr (PERB) Bp += (size_t)(row0 >> 13) * (size_t)(LDC * K);  // b = row0/8192
  const int tid  = threadIdx.x;
  const int lane = tid & 63;
  const int wave = tid >> 6;
  const int wr = (wave >> 1) << 6;
  const int wc = (wave & 1) << 6;
  const int srow = tid >> 3;
  const int scol = (tid & 7) << 3;

  f32x4 acc[4][4] = {};

  for (int k0 = 0; k0 < K; k0 += 64) {
#pragma unroll
    for (int it = 0; it < 4; ++it) {
      const unsigned short* ga = A + (size_t)(row0 + it * 32 + srow) * LDA + (k0 + scol);
      __builtin_amdgcn_global_load_lds(
          (const __attribute__((address_space(1))) void*)ga,
          (__attribute__((address_space(3))) void*)((char*)As + (it * 4096 + wave * 1024)),
          16, 0, 0);
      const unsigned short* gb = Bp + (size_t)(col0 + it * 32 + srow) * K + (k0 + scol);
      __builtin_amdgcn_global_load_lds(
          (const __attribute__((address_space(1))) void*)gb,
          (__attribute__((address_space(3))) void*)((char*)Bs + (it * 4096 + wave * 1024)),
          16, 0, 0);
    }
    __syncthreads();
#pragma unroll
    for (int ks = 0; ks < 2; ++ks) {
      bf16x8 af[4], bfr[4];
#pragma unroll
      for (int mt = 0; mt < 4; ++mt)
        af[mt] = *reinterpret_cast<const bf16x8*>(
            &As[(wr + mt * 16 + (lane & 15)) * 64 + ks * 32 + (lane >> 4) * 8]);
#pragma unroll
      for (int nt = 0; nt < 4; ++nt)
        bfr[nt] = *reinterpret_cast<const bf16x8*>(
            &Bs[(wc + nt * 16 + (lane & 15)) * 64 + ks * 32 + (lane >> 4) * 8]);
#pragma unroll
      for (int mt = 0; mt < 4; ++mt)
#pragma unroll
        for (int nt = 0; nt < 4; ++nt)
          acc[mt][nt] = __builtin_amdgcn_mfma_f32_16x16x32_bf16(af[mt], bfr[nt], acc[mt][nt], 0, 0, 0);
    }
    __syncthreads();   // also guarantees As/Bs free for epilogue reuse after last step
  }

  if constexpr (OUTF32) {
    // f32 direct stores: 16 consecutive cols x 4B = 64B per wave-row segment (full line)
#pragma unroll
    for (int mt = 0; mt < 4; ++mt) {
#pragma unroll
      for (int nt = 0; nt < 4; ++nt) {
        const int col = col0 + wc + nt * 16 + (lane & 15);
        float bv = 0.0f;
        if constexpr (BIAS) bv = bias[col];
#pragma unroll
        for (int i = 0; i < 4; ++i) {
          const int row = row0 + wr + mt * 16 + ((lane >> 4) << 2) + i;
          reinterpret_cast<float*>(Cout)[(size_t)row * LDC + col] = acc[mt][nt][i] + bv;
        }
      }
    }
  } else {
    // bf16: stage tile in LDS, then 16B-coalesced stores
    unsigned short* Ct = (unsigned short*)smem;          // [128][128]
#pragma unroll
    for (int mt = 0; mt < 4; ++mt) {
#pragma unroll
      for (int nt = 0; nt < 4; ++nt) {
        const int lc = wc + nt * 16 + (lane & 15);
        float bv = 0.0f;
        if constexpr (BIAS) bv = bias[col0 + lc];
#pragma unroll
        for (int i = 0; i < 4; ++i) {
          const int lr = wr + mt * 16 + ((lane >> 4) << 2) + i;
          Ct[lr * 128 + lc] = f2bu(acc[mt][nt][i] + bv);
        }
      }
    }
    __syncthreads();
    const int r = tid >> 1, cs = (tid & 1) << 6;         // 64 cols = 128B per thread
    unsigned short* gout = (unsigned short*)Cout + (size_t)(row0 + r) * LDC + col0 + cs;
    const unsigned short* lsrc = Ct + r * 128 + cs;
#pragma unroll
    for (int i = 0; i < 8; ++i)
      *reinterpret_cast<u16x8*>(gout + i * 8) = *reinterpret_cast<const u16x8*>(lsrc + i * 8);
  }
}

// ---------------------------------------------------------------- fused instance-norm + partial k^T v
// kvb layout [32768, 1024]: k at cols [0,512), v at [512,1024), col within = h*64+d.
// grid (32 bh, 16 chunks), block 256; 16 stages of 32 rows; f32 LDS double-buffer; no atomics.
__global__ __launch_bounds__(256) void dots_kernel(const unsigned short* __restrict__ kvb,
                                                   float* __restrict__ partial) {
  const int bh = blockIdx.x;          // 0..31
  const int chunk = blockIdx.y;       // 0..15
  const int b = bh >> 3, h = bh & 7;
  const int t = threadIdx.x;
  __shared__ float lbuf[2][4360];     // [k:32x68 | pad4 | v:32x68]

  const int r  = t >> 3;
  const int j  = t & 7;
  const int kv = j >> 2;
  const int jj = j & 3;
  const int dq = t & 15;
  const int eq = t >> 4;

  const size_t rowbase = (size_t)(b * SEQ + chunk * 512 + r) * 1024 + kv * 512 + h * 64 + jj * 16;
  const int lds_off = kv * 2180 + r * 68 + jj * 16;

  float acc[4][4] = {};
  u16x8 raw0, raw1;
  raw0 = *reinterpret_cast<const u16x8*>(kvb + rowbase);
  raw1 = *reinterpret_cast<const u16x8*>(kvb + rowbase + 8);

  int p = 0;
  {
    float x[16];
#pragma unroll
    for (int i = 0; i < 8; ++i) { x[i] = b2f(raw0[i]); x[8 + i] = b2f(raw1[i]); }
    float s = 0.f, s2 = 0.f;
#pragma unroll
    for (int i = 0; i < 16; ++i) { s += x[i]; s2 += x[i] * x[i]; }
    s += __shfl_xor(s, 1, 64);  s2 += __shfl_xor(s2, 1, 64);
    s += __shfl_xor(s, 2, 64);  s2 += __shfl_xor(s2, 2, 64);
    const float mean = s * (1.0f / 64.0f);
    float var = s2 * (1.0f / 64.0f) - mean * mean;
    var = var < 0.f ? 0.f : var;
    const float rs = rsqrtf(var + EPS);
    float* dst = &lbuf[0][lds_off];
#pragma unroll
    for (int i = 0; i < 4; ++i) {
      f32x4 o = { (x[4*i+0]-mean)*rs, (x[4*i+1]-mean)*rs, (x[4*i+2]-mean)*rs, (x[4*i+3]-mean)*rs };
      *reinterpret_cast<f32x4*>(dst + 4 * i) = o;
    }
  }

  for (int sIt = 0; sIt < 16; ++sIt) {
    const bool more = (sIt + 1) < 16;
    if (more) {
      const unsigned short* src = kvb + rowbase + (size_t)(sIt + 1) * 32 * 1024;
      raw0 = *reinterpret_cast<const u16x8*>(src);
      raw1 = *reinterpret_cast<const u16x8*>(src + 8);
    }
    __syncthreads();
    {
      const float* lk = &lbuf[p][0];
      const float* lv = &lbuf[p][2180];
#pragma unroll 4
      for (int rr = 0; rr < 32; ++rr) {
        f32x4 kf = *reinterpret_cast<const f32x4*>(lk + rr * 68 + dq * 4);
        f32x4 vf = *reinterpret_cast<const f32x4*>(lv + rr * 68 + eq * 4);
#pragma unroll
        for (int i = 0; i < 4; ++i)
#pragma unroll
          for (int jx = 0; jx < 4; ++jx)
            acc[i][jx] = fmaf(kf[i], vf[jx], acc[i][jx]);
      }
    }
    if (more) {
      float x[16];
#pragma unroll
      for (int i = 0; i < 8; ++i) { x[i] = b2f(raw0[i]); x[8 + i] = b2f(raw1[i]); }
      float s = 0.f, s2 = 0.f;
#pragma unroll
      for (int i = 0; i < 16; ++i) { s += x[i]; s2 += x[i] * x[i]; }
      s += __shfl_xor(s, 1, 64);  s2 += __shfl_xor(s2, 1, 64);
      s += __shfl_xor(s, 2, 64);  s2 += __shfl_xor(s2, 2, 64);
      const float mean = s * (1.0f / 64.0f);
      float var = s2 * (1.0f / 64.0f) - mean * mean;
      var = var < 0.f ? 0.f : var;
      const float rs = rsqrtf(var + EPS);
      float* dst = &lbuf[p ^ 1][lds_off];
#pragma unroll
      for (int i = 0; i < 4; ++i) {
        f32x4 o = { (x[4*i+0]-mean)*rs, (x[4*i+1]-mean)*rs, (x[4*i+2]-mean)*rs, (x[4*i+3]-mean)*rs };
        *reinterpret_cast<f32x4*>(dst + 4 * i) = o;
      }
    }
    p ^= 1;
  }

  float* pp = partial + ((size_t)(chunk * 32 + bh) << 12) + (size_t)(dq * 4) * 64 + eq * 4;
#pragma unroll
  for (int i = 0; i < 4; ++i) {
    f32x4 o = { acc[i][0], acc[i][1], acc[i][2], acc[i][3] };
    *reinterpret_cast<f32x4*>(pp + i * 64) = o;
  }
}

// ---------------------------------------------------------------- reduce 16 partials -> dots
__global__ __launch_bounds__(256) void reduce_kernel(const float* __restrict__ partial,
                                                     float* __restrict__ dots) {
  const int i = blockIdx.x * 256 + threadIdx.x;   // f32x4 index, 32768 total
  f32x4 s = {};
#pragma unroll
  for (int c = 0; c < 16; ++c)
    s += reinterpret_cast<const f32x4*>(partial)[(size_t)c * 32768 + i];
  reinterpret_cast<f32x4*>(dots)[i] = s;
}

// ---------------------------------------------------------------- M2[b*256+c, h*64+d] = (1/n) sum_e dots[b,h,d,e]*Wout[c,h*64+e]
__global__ __launch_bounds__(512) void m2_kernel(const float* __restrict__ dots,
                                                 const float* __restrict__ Wout,
                                                 unsigned short* __restrict__ M2) {
  const int b = blockIdx.x;
  const int c = blockIdx.y;
  const int t = threadIdx.x;
  __shared__ float wrow[512];
  wrow[t] = Wout[(size_t)c * 512 + t];
  __syncthreads();
  const int h = t >> 6, d = t & 63;
  const float* dp = dots + (size_t)(b * 8 + h) * 4096 + (size_t)d * 64;
  float s = 0.0f;
#pragma unroll 8
  for (int e = 0; e < 64; ++e) s += dp[e] * wrow[(h << 6) + e];
  M2[((size_t)b * 256 + c) * 512 + t] = f2bu(s * (1.0f / 8192.0f));
}

// ---------------------------------------------------------------- launch
extern "C" void kernel_launch(void* const* d_in, const int* in_sizes, int n_in,
                              void* d_out, int out_size, void* d_ws, size_t ws_size,
                              hipStream_t stream) {
  const float* x    = (const float*)d_in[0];   // [4,8192,256]
  const float* Wqkv = (const float*)d_in[1];   // [1536,256]
  const float* Wout = (const float*)d_in[2];   // [256,512]
  const float* bout = (const float*)d_in[3];   // [256]
  char* ws = (char*)d_ws;
  // workspace layout (16B aligned), total ~95.4 MB (no aliasing):
  unsigned short* xb    = (unsigned short*)(ws);                 // 16,777,216 B
  unsigned short* wqkvb = (unsigned short*)(ws + 16777216);      //    786,432 B
  unsigned short* wqT   = (unsigned short*)(ws + 17563648);      //    262,144 B  [256,512]
  unsigned short* kvb   = (unsigned short*)(ws + 17825792);      // 67,108,864 B  [32768,1024]
  float*          part  = (float*)         (ws + 84934656);      //  8,388,608 B
  float*          dots  = (float*)         (ws + 93323264);      //    524,288 B
  unsigned short* m2    = (unsigned short*)(ws + 93847552);      //  1,048,576 B  [1024,512]
  unsigned short* w3    = (unsigned short*)(ws + 94896128);      //    524,288 B  [1024,256]

  convert_kernel<<<dim3(8192), 256, 0, stream>>>(x, xb, 2097152);
  wprep_kernel<<<dim3(384), 256, 0, stream>>>(Wqkv, wqkvb, wqT);
  // kv = x @ Wkv^T  -> bf16 [32768,1024]  (q never materialized)
  gemm_kernel<256, 256, 1024, false, false, false><<<dim3(8, 256), 256, 0, stream>>>(
      xb, wqkvb + (size_t)512 * 256, nullptr, kvb);
  // fused instance-norm + k^T v partials
  dots_kernel<<<dim3(32, 16), 256, 0, stream>>>(kvb, part);
  reduce_kernel<<<dim3(128), 256, 0, stream>>>(part, dots);
  // M2 = (1/n) dots @ Wout  (bf16 [1024,512])
  m2_kernel<<<dim3(4, 256), 512, 0, stream>>>(dots, Wout, m2);
  // W3 = M2 @ Wq^T  (bf16 [1024,256], per-batch [4][256][256])
  gemm_kernel<512, 512, 256, false, false, false><<<dim3(2, 8), 256, 0, stream>>>(m2, wqT, nullptr, w3);
  // out = x @ W3^T + bout  -> f32 [32768,256]
  gemm_kernel<256, 256, 256, true, true, true><<<dim3(2, 256), 256, 0, stream>>>(xb, w3, bout, d_out);
}